// Round 1
// baseline (750.966 us; speedup 1.0000x reference)
//
#include <hip/hip_runtime.h>

// Problem constants (from reference setup_inputs)
constexpr int BB    = 2;
constexpr int NN    = 50000;
constexpr int CC    = 64;     // channels == wave size
constexpr int MM    = 50000;
constexpr int KK    = 16;     // neighbors
constexpr int HH    = 8;      // heads -> C/H = 8 channels per head
constexpr int CMID  = 16;

// One wave (64 lanes) per (b,m). Lane = channel c. Each lane accumulates
// out[c, 0..15] in registers. out[b,m,c*CMID+w].
__global__ __launch_bounds__(256) void pcf_kernel(
    const float* __restrict__ feat,   // [B,N,C]
    const int*   __restrict__ inds,   // [B,M,K]
    const float* __restrict__ guid,   // [B,M,K,H]
    const float* __restrict__ wnet,   // [B,M,K,CMID]
    float*       __restrict__ out)    // [B,M,C*CMID]
{
    const int wid  = blockIdx.x * (blockDim.x >> 6) + (threadIdx.x >> 6);
    const int lane = threadIdx.x & 63;
    if (wid >= BB * MM) return;

    const int b = wid / MM;

    const float*  fbase = feat + (size_t)b * NN * CC;
    const int*    idx   = inds + (size_t)wid * KK;
    const float*  gd    = guid + (size_t)wid * KK * HH;
    const float4* wn4   = (const float4*)(wnet + (size_t)wid * KK * CMID);

    // Preload the 16 neighbor indices (lanes 16..63 load duplicates; one txn)
    int myidx = idx[lane & (KK - 1)];

    float acc[CMID];
#pragma unroll
    for (int i = 0; i < CMID; ++i) acc[i] = 0.f;

    const int h = lane >> 3;  // head for this channel

#pragma unroll
    for (int k = 0; k < KK; ++k) {
        const int id = __shfl(myidx, k);          // wave-uniform neighbor index
        const float g = gd[k * HH + h];           // 8 distinct floats / wave
        const float f = fbase[(size_t)id * CC + lane] * g;  // coalesced 256B row

        const float4 w0 = wn4[k * 4 + 0];         // wave-uniform broadcasts
        const float4 w1 = wn4[k * 4 + 1];
        const float4 w2 = wn4[k * 4 + 2];
        const float4 w3 = wn4[k * 4 + 3];

        acc[0]  += f * w0.x;  acc[1]  += f * w0.y;
        acc[2]  += f * w0.z;  acc[3]  += f * w0.w;
        acc[4]  += f * w1.x;  acc[5]  += f * w1.y;
        acc[6]  += f * w1.z;  acc[7]  += f * w1.w;
        acc[8]  += f * w2.x;  acc[9]  += f * w2.y;
        acc[10] += f * w2.z;  acc[11] += f * w2.w;
        acc[12] += f * w3.x;  acc[13] += f * w3.y;
        acc[14] += f * w3.z;  acc[15] += f * w3.w;
    }

    // Store: lane c owns out[wid, c*16 .. c*16+15] -> 4 contiguous float4
    float4* o = (float4*)(out + (size_t)wid * (CC * CMID) + (size_t)lane * CMID);
    o[0] = make_float4(acc[0],  acc[1],  acc[2],  acc[3]);
    o[1] = make_float4(acc[4],  acc[5],  acc[6],  acc[7]);
    o[2] = make_float4(acc[8],  acc[9],  acc[10], acc[11]);
    o[3] = make_float4(acc[12], acc[13], acc[14], acc[15]);
}

extern "C" void kernel_launch(void* const* d_in, const int* in_sizes, int n_in,
                              void* d_out, int out_size, void* d_ws, size_t ws_size,
                              hipStream_t stream) {
    const float* feat = (const float*)d_in[0];   // [B,N,C] fp32
    const int*   inds = (const int*)d_in[1];     // [B,M,K] int
    const float* guid = (const float*)d_in[2];   // [B,M,K,H] fp32
    const float* wnet = (const float*)d_in[3];   // [B,M,K,CMID] fp32
    float*       out  = (float*)d_out;           // [B,M,C*CMID] fp32

    const int total_waves = BB * MM;             // 100000
    const int waves_per_block = 4;               // 256 threads
    const int blocks = (total_waves + waves_per_block - 1) / waves_per_block;

    pcf_kernel<<<blocks, 256, 0, stream>>>(feat, inds, guid, wnet, out);
}